// Round 1
// baseline (132.733 us; speedup 1.0000x reference)
//
#include <hip/hip_runtime.h>
#include <math.h>

#define B_ 4
#define T_ 512
#define D_ 64
#define EPS 1e-8f
#define ROWS 4   // query rows per attn block

__device__ __forceinline__ float wave_sum(float v) {
#pragma unroll
  for (int m = 1; m < 64; m <<= 1) v += __shfl_xor(v, m, 64);
  return v;
}
__device__ __forceinline__ float wave_max(float v) {
#pragma unroll
  for (int m = 1; m < 64; m <<= 1) v = fmaxf(v, __shfl_xor(v, m, 64));
  return v;
}

// ---- p = double-normalized softplus simplex; stored transposed pT[b][d][t] ----
__global__ __launch_bounds__(256) void proj_kernel(const float* __restrict__ x,
                                                   float* __restrict__ pT) {
  int wave = threadIdx.x >> 6, lane = threadIdx.x & 63;
  int row = blockIdx.x * 4 + wave;        // (b,t) flat, 0..2047
  int b = row >> 9, t = row & 511;
  float xv = x[row * D_ + lane];
  // stable softplus = max(x,0) + log1p(exp(-|x|))  (== jnp.logaddexp(x,0))
  float sp = fmaxf(xv, 0.0f) + log1pf(expf(-fabsf(xv)));
  float s1 = wave_sum(sp);
  float p = sp / (s1 + EPS);
  p = fmaxf(p, EPS);
  float s2 = wave_sum(p);
  p = p / (s2 + EPS);
  pT[(b * D_ + lane) * T_ + t] = p;
}

// ---- fused: FR inner -> logits -> softmax -> w@x -> residual update ----
__global__ __launch_bounds__(256) void attn_kernel(const float* __restrict__ x,
                                                   const float* __restrict__ pT,
                                                   const float* __restrict__ rsp,
                                                   float* __restrict__ xout) {
  int b = blockIdx.y;
  int i0 = blockIdx.x * ROWS;
  __shared__ float4 pi4[ROWS][D_ / 4];     // 1 KB
  __shared__ float wbuf[ROWS][T_];         // 8 KB (logits, then exp-weights)
  __shared__ float rowsum[ROWS];
  __shared__ float partial[4][ROWS][D_];   // 4 KB
  int tid = threadIdx.x;

  {  // load the 4 query rows' p vectors (strided gather from pT)
    int r = tid >> 6, d = tid & 63;
    ((float*)&pi4[r][0])[d] = pT[(b * D_ + d) * T_ + i0 + r];
  }
  __syncthreads();

  const float* pb = pT + b * D_ * T_;
#pragma unroll
  for (int jj = 0; jj < 2; ++jj) {
    int j = tid + jj * 256;
    float s0 = 0.f, s1 = 0.f, s2 = 0.f, s3 = 0.f;
    const float* pc = pb + j;
#pragma unroll 4
    for (int d4 = 0; d4 < D_ / 4; ++d4) {
      float pj0 = pc[(d4 * 4 + 0) * T_];   // coalesced: lanes = consecutive j
      float pj1 = pc[(d4 * 4 + 1) * T_];
      float pj2 = pc[(d4 * 4 + 2) * T_];
      float pj3 = pc[(d4 * 4 + 3) * T_];
      float4 q0 = pi4[0][d4], q1 = pi4[1][d4], q2 = pi4[2][d4], q3 = pi4[3][d4];
      s0 += __builtin_amdgcn_sqrtf(fmaf(q0.x, pj0, EPS));
      s0 += __builtin_amdgcn_sqrtf(fmaf(q0.y, pj1, EPS));
      s0 += __builtin_amdgcn_sqrtf(fmaf(q0.z, pj2, EPS));
      s0 += __builtin_amdgcn_sqrtf(fmaf(q0.w, pj3, EPS));
      s1 += __builtin_amdgcn_sqrtf(fmaf(q1.x, pj0, EPS));
      s1 += __builtin_amdgcn_sqrtf(fmaf(q1.y, pj1, EPS));
      s1 += __builtin_amdgcn_sqrtf(fmaf(q1.z, pj2, EPS));
      s1 += __builtin_amdgcn_sqrtf(fmaf(q1.w, pj3, EPS));
      s2 += __builtin_amdgcn_sqrtf(fmaf(q2.x, pj0, EPS));
      s2 += __builtin_amdgcn_sqrtf(fmaf(q2.y, pj1, EPS));
      s2 += __builtin_amdgcn_sqrtf(fmaf(q2.z, pj2, EPS));
      s2 += __builtin_amdgcn_sqrtf(fmaf(q2.w, pj3, EPS));
      s3 += __builtin_amdgcn_sqrtf(fmaf(q3.x, pj0, EPS));
      s3 += __builtin_amdgcn_sqrtf(fmaf(q3.y, pj1, EPS));
      s3 += __builtin_amdgcn_sqrtf(fmaf(q3.z, pj2, EPS));
      s3 += __builtin_amdgcn_sqrtf(fmaf(q3.w, pj3, EPS));
    }
    float ss[ROWS] = {s0, s1, s2, s3};
#pragma unroll
    for (int r = 0; r < ROWS; ++r) {
      float inner = fminf(fmaxf(ss[r], -1.0f + 1e-6f), 1.0f - 1e-6f);
      wbuf[r][j] = -2.0f * acosf(inner);   // logits (temperature = 1)
    }
  }
  __syncthreads();

  {  // softmax: wave r owns row r
    int r = tid >> 6, lane = tid & 63;
    float m = -1e30f;
#pragma unroll
    for (int k = 0; k < 8; ++k) m = fmaxf(m, wbuf[r][lane + 64 * k]);
    m = wave_max(m);
    float s = 0.f;
#pragma unroll
    for (int k = 0; k < 8; ++k) {
      float e = __expf(wbuf[r][lane + 64 * k] - m);
      wbuf[r][lane + 64 * k] = e;
      s += e;
    }
    s = wave_sum(s);
    if (lane == 0) rowsum[r] = s;
  }
  __syncthreads();

  {  // x_attn = w @ x  (unnormalized; divide by rowsum at the end)
    int d = tid & 63, c = tid >> 6;
    const float* xb = x + b * T_ * D_;
    float a0 = 0.f, a1 = 0.f, a2 = 0.f, a3 = 0.f;
    for (int j = c * 128; j < c * 128 + 128; ++j) {
      float xv = xb[j * D_ + d];           // coalesced: lanes = consecutive d
      a0 = fmaf(wbuf[0][j], xv, a0);
      a1 = fmaf(wbuf[1][j], xv, a1);
      a2 = fmaf(wbuf[2][j], xv, a2);
      a3 = fmaf(wbuf[3][j], xv, a3);
    }
    partial[c][0][d] = a0;
    partial[c][1][d] = a1;
    partial[c][2][d] = a2;
    partial[c][3][d] = a3;
  }
  __syncthreads();

  {  // x' = 0.5(1-c)x + 0.5(1+c)x_attn, c = 0.01*residual_scale
    int r = tid >> 6, d = tid & 63;
    float xa = (partial[0][r][d] + partial[1][r][d] + partial[2][r][d] +
                partial[3][r][d]) / rowsum[r];
    int idx = (b * T_ + i0 + r) * D_ + d;
    float c01 = 0.01f * rsp[0];
    xout[idx] = 0.5f * (1.0f - c01) * x[idx] + 0.5f * (1.0f + c01) * xa;
  }
}

// ---- phi (corr offdiag abs mean) + kappa (mean row norm), 1 block per b ----
__global__ __launch_bounds__(256) void phikappa_kernel(const float* __restrict__ x,
                                                       float* __restrict__ out) {
  int b = blockIdx.x;
  const float* xb = x + b * T_ * D_;
  __shared__ float mean[D_];
  __shared__ float part[4][D_];
  __shared__ float tile[64][D_];           // 16 KB, centered t-tile
  __shared__ float lvar[D_];
  __shared__ float red[4];
  __shared__ float phired[4];
  int tid = threadIdx.x;
  int d = tid & 63, c = tid >> 6;

  // column-sum partials for mean
  float s = 0.f;
  for (int t = c * 128; t < c * 128 + 128; ++t) s += xb[t * D_ + d];
  part[c][d] = s;

  // kappa: 2 rows per thread
  float ks = 0.f;
  for (int t = tid; t < T_; t += 256) {
    const float4* xr = (const float4*)(xb + t * D_);
    float ss = 0.f;
#pragma unroll
    for (int q = 0; q < 16; ++q) {
      float4 v = xr[q];
      ss += v.x * v.x + v.y * v.y + v.z * v.z + v.w * v.w;
    }
    ks += sqrtf(ss);
  }
  ks = wave_sum(ks);
  if ((tid & 63) == 0) red[tid >> 6] = ks;
  __syncthreads();
  if (tid < 64) mean[tid] = (part[0][tid] + part[1][tid] + part[2][tid] +
                             part[3][tid]) * (1.0f / 512.0f);
  float kappa = (red[0] + red[1] + red[2] + red[3]) * (1.0f / 512.0f);
  __syncthreads();  // mean ready

  // covariance: thread owns (dd, ebase..ebase+15)
  int dd = tid >> 2;
  int ebase = (tid & 3) * 16;
  float acc[16];
#pragma unroll
  for (int k = 0; k < 16; ++k) acc[k] = 0.f;

  for (int t0 = 0; t0 < T_; t0 += 64) {
    {  // cooperative centered tile load, float4
      const float4* src = (const float4*)(xb + t0 * D_);
      float4* dst = (float4*)&tile[0][0];
      const float4* m4 = (const float4*)mean;
#pragma unroll
      for (int q = 0; q < 4; ++q) {
        int idx = tid + q * 256;           // 0..1023 float4s
        float4 v = src[idx];
        float4 mv = m4[idx & 15];
        v.x -= mv.x; v.y -= mv.y; v.z -= mv.z; v.w -= mv.w;
        dst[idx] = v;
      }
    }
    __syncthreads();
    for (int tt = 0; tt < 64; ++tt) {
      float xd = tile[tt][dd];
      const float4* te = (const float4*)&tile[tt][ebase];
      float4 v0 = te[0], v1 = te[1], v2 = te[2], v3 = te[3];
      acc[0]  = fmaf(xd, v0.x, acc[0]);  acc[1]  = fmaf(xd, v0.y, acc[1]);
      acc[2]  = fmaf(xd, v0.z, acc[2]);  acc[3]  = fmaf(xd, v0.w, acc[3]);
      acc[4]  = fmaf(xd, v1.x, acc[4]);  acc[5]  = fmaf(xd, v1.y, acc[5]);
      acc[6]  = fmaf(xd, v1.z, acc[6]);  acc[7]  = fmaf(xd, v1.w, acc[7]);
      acc[8]  = fmaf(xd, v2.x, acc[8]);  acc[9]  = fmaf(xd, v2.y, acc[9]);
      acc[10] = fmaf(xd, v2.z, acc[10]); acc[11] = fmaf(xd, v2.w, acc[11]);
      acc[12] = fmaf(xd, v3.x, acc[12]); acc[13] = fmaf(xd, v3.y, acc[13]);
      acc[14] = fmaf(xd, v3.z, acc[14]); acc[15] = fmaf(xd, v3.w, acc[15]);
    }
    __syncthreads();
  }
#pragma unroll
  for (int k = 0; k < 16; ++k) acc[k] *= (1.0f / 512.0f);  // /(T+EPS), fp32 == 512

  if (dd >= ebase && dd < ebase + 16) lvar[dd] = fmaxf(acc[dd - ebase], EPS);
  __syncthreads();

  float vd = lvar[dd];
  float psum = 0.f;
#pragma unroll
  for (int k = 0; k < 16; ++k) {
    int e = ebase + k;
    if (e == dd) continue;                 // offdiag mask
    float denom = fmaxf(sqrtf(vd * lvar[e]), EPS);
    float cc = acc[k] / denom;
    cc = fminf(fmaxf(cc, -1.0f), 1.0f);
    psum += fabsf(cc);
  }
  psum = wave_sum(psum);
  if ((tid & 63) == 0) phired[tid >> 6] = psum;
  __syncthreads();
  if (tid == 0) {
    float phi = (phired[0] + phired[1] + phired[2] + phired[3]) * (1.0f / 4096.0f);
    out[B_ * T_ * D_ + b] = phi;
    out[B_ * T_ * D_ + B_ + b] = kappa;
  }
}

extern "C" void kernel_launch(void* const* d_in, const int* in_sizes, int n_in,
                              void* d_out, int out_size, void* d_ws, size_t ws_size,
                              hipStream_t stream) {
  const float* x0 = (const float*)d_in[0];
  const float* rs = (const float*)d_in[1];
  float* out = (float*)d_out;
  float* pT = (float*)d_ws;                          // 512 KB: p transposed [b][d][t]
  float* x1 = (float*)d_ws + B_ * T_ * D_;           // 512 KB: intermediate x

  dim3 ablk(256), agrd(T_ / ROWS, B_);
  // iteration 1: x0 -> x1
  proj_kernel<<<(B_ * T_) / 4, 256, 0, stream>>>(x0, pT);
  attn_kernel<<<agrd, ablk, 0, stream>>>(x0, pT, rs, x1);
  // iteration 2: x1 -> out (x region)
  proj_kernel<<<(B_ * T_) / 4, 256, 0, stream>>>(x1, pT);
  attn_kernel<<<agrd, ablk, 0, stream>>>(x1, pT, rs, out);
  // epilogue: phi + kappa from final x
  phikappa_kernel<<<B_, 256, 0, stream>>>(out, out);
}

// Round 2
// 104.327 us; speedup vs baseline: 1.2723x; 1.2723x over previous
//
#include <hip/hip_runtime.h>
#include <math.h>

#define B_ 4
#define T_ 512
#define D_ 64
#define EPS 1e-8f

__device__ __forceinline__ float wave_sum(float v) {
#pragma unroll
  for (int m = 1; m < 64; m <<= 1) v += __shfl_xor(v, m, 64);
  return v;
}
__device__ __forceinline__ float wave_max(float v) {
#pragma unroll
  for (int m = 1; m < 64; m <<= 1) v = fmaxf(v, __shfl_xor(v, m, 64));
  return v;
}
__device__ __forceinline__ float softplus_f(float x) {
  return fmaxf(x, 0.0f) + log1pf(expf(-fabsf(x)));
}

// ---- s = sqrt(double-normalized softplus simplex), row-major (coalesced) ----
__global__ __launch_bounds__(256) void proj_kernel(const float* __restrict__ x,
                                                   float* __restrict__ s) {
  int wave = threadIdx.x >> 6, lane = threadIdx.x & 63;
  int row = blockIdx.x * 4 + wave;  // (b,t) flat
  float sp = softplus_f(x[row * D_ + lane]);
  float s1 = wave_sum(sp);
  float p = sp / (s1 + EPS);
  p = fmaxf(p, EPS);
  float s2 = wave_sum(p);
  s[row * D_ + lane] = sqrtf(p / (s2 + EPS));
}

// ---- logits: 64x64 tile of -2*acos(clip(s_i . s_j)) ----
__global__ __launch_bounds__(256) void logits_kernel(const float* __restrict__ s,
                                                     float* __restrict__ L) {
  int jt = blockIdx.x, it = blockIdx.y, b = blockIdx.z;
  __shared__ float si[64][68];
  __shared__ float sj[64][68];
  int tid = threadIdx.x;
  const float* sb = s + b * T_ * D_;
#pragma unroll
  for (int k = 0; k < 4; ++k) {  // 1024 float4s per tile
    int idx = tid + k * 256;
    int row = idx >> 4, c4 = idx & 15;
    *(float4*)&si[row][c4 * 4] = *(const float4*)(sb + (it * 64 + row) * D_ + c4 * 4);
    *(float4*)&sj[row][c4 * 4] = *(const float4*)(sb + (jt * 64 + row) * D_ + c4 * 4);
  }
  __syncthreads();

  int i4 = tid >> 4, j4 = tid & 15;  // i = i4 + 16a, j = j4 + 16c
  float acc[4][4];
#pragma unroll
  for (int a = 0; a < 4; ++a)
#pragma unroll
    for (int c = 0; c < 4; ++c) acc[a][c] = 0.f;

#pragma unroll 4
  for (int d4 = 0; d4 < 16; ++d4) {
    float4 A[4], Bv[4];
#pragma unroll
    for (int a = 0; a < 4; ++a) A[a] = *(const float4*)&si[i4 + 16 * a][d4 * 4];
#pragma unroll
    for (int c = 0; c < 4; ++c) Bv[c] = *(const float4*)&sj[j4 + 16 * c][d4 * 4];
#pragma unroll
    for (int a = 0; a < 4; ++a)
#pragma unroll
      for (int c = 0; c < 4; ++c) {
        acc[a][c] = fmaf(A[a].x, Bv[c].x, acc[a][c]);
        acc[a][c] = fmaf(A[a].y, Bv[c].y, acc[a][c]);
        acc[a][c] = fmaf(A[a].z, Bv[c].z, acc[a][c]);
        acc[a][c] = fmaf(A[a].w, Bv[c].w, acc[a][c]);
      }
  }
#pragma unroll
  for (int a = 0; a < 4; ++a) {
    int i = it * 64 + i4 + 16 * a;
    float* Lr = L + ((size_t)(b * T_) + i) * T_ + jt * 64;
#pragma unroll
    for (int c = 0; c < 4; ++c) {
      float inner = fminf(fmaxf(acc[a][c], -1.0f + 1e-6f), 1.0f - 1e-6f);
      Lr[j4 + 16 * c] = -2.0f * acosf(inner);
    }
  }
}

// ---- apply: row softmax + x_attn = w@x + residual (+ fused next-iter s) ----
__global__ __launch_bounds__(256) void apply_kernel(const float* __restrict__ L,
                                                    const float* __restrict__ xin,
                                                    const float* __restrict__ rsp,
                                                    float* __restrict__ xout,
                                                    float* __restrict__ sout) {
  int b = blockIdx.y;
  int i0 = blockIdx.x * 8;   // 8 query rows per block
  __shared__ float wR[8][512];     // normalized weights, row-major
  __shared__ float red[4][8][64];  // cross-wave partials
  int tid = threadIdx.x;
  int w = tid >> 6, lane = tid & 63;

  // phase 1: softmax rows (wave handles 2 rows)
#pragma unroll
  for (int r = 0; r < 2; ++r) {
    int i = w * 2 + r;
    const float* Lr = L + ((size_t)(b * T_) + i0 + i) * T_;
    float4 v0 = ((const float4*)Lr)[lane];
    float4 v1 = ((const float4*)Lr)[64 + lane];
    float m = fmaxf(fmaxf(fmaxf(v0.x, v0.y), fmaxf(v0.z, v0.w)),
                    fmaxf(fmaxf(v1.x, v1.y), fmaxf(v1.z, v1.w)));
    m = wave_max(m);
    float4 e0, e1;
    e0.x = __expf(v0.x - m); e0.y = __expf(v0.y - m);
    e0.z = __expf(v0.z - m); e0.w = __expf(v0.w - m);
    e1.x = __expf(v1.x - m); e1.y = __expf(v1.y - m);
    e1.z = __expf(v1.z - m); e1.w = __expf(v1.w - m);
    float ssum = wave_sum(e0.x + e0.y + e0.z + e0.w + e1.x + e1.y + e1.z + e1.w);
    float inv = 1.0f / ssum;
    e0.x *= inv; e0.y *= inv; e0.z *= inv; e0.w *= inv;
    e1.x *= inv; e1.y *= inv; e1.z *= inv; e1.w *= inv;
    *(float4*)&wR[i][lane * 4] = e0;
    *(float4*)&wR[i][256 + lane * 4] = e1;
  }
  __syncthreads();

  // phase 2: register-tiled w@x. thread = (dg = d-group of 4, js = j-slice)
  int dg = tid & 15, js = tid >> 4;
  float acc[8][4];
#pragma unroll
  for (int i = 0; i < 8; ++i)
#pragma unroll
    for (int k = 0; k < 4; ++k) acc[i][k] = 0.f;

  const float* xb = xin + (size_t)(b * T_) * D_;
#pragma unroll 2
  for (int jj = 0; jj < 8; ++jj) {
    int jbase = jj * 64 + js * 4;
    float xr[4][4];
#pragma unroll
    for (int c = 0; c < 4; ++c) {
      float4 xv = *(const float4*)(xb + (jbase + c) * D_ + dg * 4);
      xr[c][0] = xv.x; xr[c][1] = xv.y; xr[c][2] = xv.z; xr[c][3] = xv.w;
    }
#pragma unroll
    for (int i = 0; i < 8; ++i) {
      float4 wv = *(const float4*)&wR[i][jbase];
      float wc[4] = {wv.x, wv.y, wv.z, wv.w};
#pragma unroll
      for (int c = 0; c < 4; ++c)
#pragma unroll
        for (int k = 0; k < 4; ++k)
          acc[i][k] = fmaf(wc[c], xr[c][k], acc[i][k]);
    }
  }

  // phase 3: reduce over js (bits 4,5 of lane are js low bits; wave spans 4 js)
#pragma unroll
  for (int i = 0; i < 8; ++i)
#pragma unroll
    for (int k = 0; k < 4; ++k) {
      float v = acc[i][k];
      v += __shfl_xor(v, 16, 64);
      v += __shfl_xor(v, 32, 64);
      acc[i][k] = v;
    }
  if (lane < 16) {
#pragma unroll
    for (int i = 0; i < 8; ++i)
      *(float4*)&red[w][i][lane * 4] =
          make_float4(acc[i][0], acc[i][1], acc[i][2], acc[i][3]);
  }
  __syncthreads();

  // final: residual + write x, fused s of new x (wave w owns rows w and w+4)
  float c01 = 0.01f * rsp[0];
#pragma unroll
  for (int h = 0; h < 2; ++h) {
    int i = w + 4 * h, d = lane;
    float xa = red[0][i][d] + red[1][i][d] + red[2][i][d] + red[3][i][d];
    size_t idx = ((size_t)(b * T_) + i0 + i) * D_ + d;
    float xn = 0.5f * (1.0f - c01) * xin[idx] + 0.5f * (1.0f + c01) * xa;
    xout[idx] = xn;
    float sp = softplus_f(xn);
    float s1 = wave_sum(sp);
    float p = sp / (s1 + EPS);
    p = fmaxf(p, EPS);
    float s2 = wave_sum(p);
    sout[idx] = sqrtf(p / (s2 + EPS));
  }
}

// ---- P1: per-slice partials: sum(x), sum(x_d x_e), sum(||x_t||) ----
__global__ __launch_bounds__(256) void p1_kernel(const float* __restrict__ x,
                                                 float* __restrict__ covp,
                                                 float* __restrict__ meanp,
                                                 float* __restrict__ kappap) {
  int blk = blockIdx.x;
  int b = blk >> 3, sl = blk & 7;
  const float* xb = x + ((size_t)(b * T_) + sl * 64) * D_;
  __shared__ float tile[64][68];
  __shared__ float red2[4][64];
  __shared__ float kred[4];
  int tid = threadIdx.x;
#pragma unroll
  for (int k = 0; k < 4; ++k) {
    int idx = tid + k * 256;
    int row = idx >> 4, c4 = idx & 15;
    *(float4*)&tile[row][c4 * 4] = *(const float4*)(xb + row * D_ + c4 * 4);
  }
  __syncthreads();

  // mean partial
  {
    int d = tid & 63, q = tid >> 6;
    float ms = 0.f;
#pragma unroll
    for (int tt = 0; tt < 16; ++tt) ms += tile[q * 16 + tt][d];
    red2[q][d] = ms;
  }

  // kappa partial: thread (tr = row, qq = d-quarter)
  {
    int tr = tid >> 2, qq = tid & 3;
    float ksq = 0.f;
#pragma unroll
    for (int k = 0; k < 16; ++k) {
      float v = tile[tr][qq * 16 + k];
      ksq = fmaf(v, v, ksq);
    }
    ksq += __shfl_xor(ksq, 1, 64);
    ksq += __shfl_xor(ksq, 2, 64);
    float contrib = (qq == 0) ? sqrtf(ksq) : 0.f;
    contrib = wave_sum(contrib);
    if ((tid & 63) == 0) kred[tid >> 6] = contrib;
  }

  // cov partial: thread (dd, e16): 16 e's
  int dd = tid >> 2, e16 = tid & 3;
  float acc[16];
#pragma unroll
  for (int k = 0; k < 16; ++k) acc[k] = 0.f;
  for (int tt = 0; tt < 64; ++tt) {
    float xd = tile[tt][dd];
    const float4* te = (const float4*)&tile[tt][e16 * 16];
    float4 v0 = te[0], v1 = te[1], v2 = te[2], v3 = te[3];
    acc[0]  = fmaf(xd, v0.x, acc[0]);  acc[1]  = fmaf(xd, v0.y, acc[1]);
    acc[2]  = fmaf(xd, v0.z, acc[2]);  acc[3]  = fmaf(xd, v0.w, acc[3]);
    acc[4]  = fmaf(xd, v1.x, acc[4]);  acc[5]  = fmaf(xd, v1.y, acc[5]);
    acc[6]  = fmaf(xd, v1.z, acc[6]);  acc[7]  = fmaf(xd, v1.w, acc[7]);
    acc[8]  = fmaf(xd, v2.x, acc[8]);  acc[9]  = fmaf(xd, v2.y, acc[9]);
    acc[10] = fmaf(xd, v2.z, acc[10]); acc[11] = fmaf(xd, v2.w, acc[11]);
    acc[12] = fmaf(xd, v3.x, acc[12]); acc[13] = fmaf(xd, v3.y, acc[13]);
    acc[14] = fmaf(xd, v3.z, acc[14]); acc[15] = fmaf(xd, v3.w, acc[15]);
  }
  float* cp = covp + (size_t)blk * 4096 + dd * 64 + e16 * 16;
#pragma unroll
  for (int kk = 0; kk < 4; ++kk)
    *(float4*)(cp + kk * 4) =
        make_float4(acc[kk * 4], acc[kk * 4 + 1], acc[kk * 4 + 2], acc[kk * 4 + 3]);
  __syncthreads();
  if (tid < 64)
    meanp[blk * 64 + tid] = red2[0][tid] + red2[1][tid] + red2[2][tid] + red2[3][tid];
  if (tid == 0) kappap[blk] = kred[0] + kred[1] + kred[2] + kred[3];
}

// ---- P2: finalize phi + kappa per batch ----
__global__ __launch_bounds__(256) void p2_kernel(const float* __restrict__ covp,
                                                 const float* __restrict__ meanp,
                                                 const float* __restrict__ kappap,
                                                 float* __restrict__ out) {
  int b = blockIdx.x;
  __shared__ float mu[64];
  __shared__ float var[64];
  __shared__ float phired[4];
  int tid = threadIdx.x;
  if (tid < 64) {
    float m = 0.f;
#pragma unroll
    for (int s = 0; s < 8; ++s) m += meanp[(b * 8 + s) * 64 + tid];
    mu[tid] = m * (1.0f / 512.0f);
  }
  __syncthreads();

  int dd = tid >> 2, e16 = tid & 3;
  float acc[16];
#pragma unroll
  for (int k = 0; k < 16; ++k) acc[k] = 0.f;
#pragma unroll
  for (int s = 0; s < 8; ++s) {
    const float* cp = covp + (size_t)(b * 8 + s) * 4096 + dd * 64 + e16 * 16;
#pragma unroll
    for (int kk = 0; kk < 4; ++kk) {
      float4 v = *(const float4*)(cp + kk * 4);
      acc[kk * 4] += v.x; acc[kk * 4 + 1] += v.y;
      acc[kk * 4 + 2] += v.z; acc[kk * 4 + 3] += v.w;
    }
  }
  float mud = mu[dd];
#pragma unroll
  for (int k = 0; k < 16; ++k)
    acc[k] = acc[k] * (1.0f / 512.0f) - mud * mu[e16 * 16 + k];  // cov
  if ((dd >> 4) == e16) var[dd] = fmaxf(acc[dd & 15], EPS);
  __syncthreads();

  float vd = var[dd];
  float psum = 0.f;
#pragma unroll
  for (int k = 0; k < 16; ++k) {
    int e = e16 * 16 + k;
    if (e == dd) continue;
    float denom = fmaxf(sqrtf(vd * var[e]), EPS);
    float cc = fminf(fmaxf(acc[k] / denom, -1.0f), 1.0f);
    psum += fabsf(cc);
  }
  psum = wave_sum(psum);
  if ((tid & 63) == 0) phired[tid >> 6] = psum;
  __syncthreads();
  if (tid == 0) {
    out[B_ * T_ * D_ + b] = (phired[0] + phired[1] + phired[2] + phired[3]) *
                            (1.0f / 4096.0f);
    float ks = 0.f;
#pragma unroll
    for (int s = 0; s < 8; ++s) ks += kappap[b * 8 + s];
    out[B_ * T_ * D_ + B_ + b] = ks * (1.0f / 512.0f);
  }
}

extern "C" void kernel_launch(void* const* d_in, const int* in_sizes, int n_in,
                              void* d_out, int out_size, void* d_ws, size_t ws_size,
                              hipStream_t stream) {
  const float* x0 = (const float*)d_in[0];
  const float* rs = (const float*)d_in[1];
  float* out = (float*)d_out;
  float* s     = (float*)d_ws;                 // 131072 floats
  float* L     = s + B_ * T_ * D_;             // 1048576 floats
  float* x1    = L + B_ * T_ * T_;             // 131072 floats
  float* covp  = x1 + B_ * T_ * D_;            // 32*4096
  float* meanp = covp + 32 * 4096;             // 32*64
  float* kappap = meanp + 32 * 64;             // 32

  dim3 lgrd(8, 8, 4), agrd(64, 4);
  proj_kernel<<<(B_ * T_) / 4, 256, 0, stream>>>(x0, s);
  logits_kernel<<<lgrd, 256, 0, stream>>>(s, L);
  apply_kernel<<<agrd, 256, 0, stream>>>(L, x0, rs, x1, s);   // writes s of x1
  logits_kernel<<<lgrd, 256, 0, stream>>>(s, L);
  apply_kernel<<<agrd, 256, 0, stream>>>(L, x1, rs, out, s);  // s write = scratch
  p1_kernel<<<32, 256, 0, stream>>>(out, covp, meanp, kappap);
  p2_kernel<<<4, 256, 0, stream>>>(covp, meanp, kappap, out);
}